// Round 6
// baseline (185.246 us; speedup 1.0000x reference)
//
#include <hip/hip_runtime.h>
#include <math.h>

#define BB 2
#define NN 1024
#define CC 256
#define NQ 100
#define HALF 128

typedef __attribute__((ext_vector_type(8))) short bf16x8;
typedef __attribute__((ext_vector_type(4))) float f32x4;

// gelu via A&S 7.1.26 erf: |err| <= 3e-7 abs; 1 rcp, no exp.
__device__ __forceinline__ float gelu_fast(float x) {
    float a = fabsf(0.70710678118654752f * x);
    float t = fmaf(a, 4.30638e-5f, 2.765672e-4f);
    t = fmaf(a, t, 1.520143e-4f);
    t = fmaf(a, t, 9.2705272e-3f);
    t = fmaf(a, t, 4.22820123e-2f);
    t = fmaf(a, t, 7.05230784e-2f);
    float p = fmaf(a, t, 1.0f);
    float p2 = p * p;
    float p4 = p2 * p2;
    float p8 = p4 * p4;
    float p16 = p8 * p8;
    float r = 0.5f * __builtin_amdgcn_rcpf(p16);   // 0.5*(1-erf(a))
    float phi = (x >= 0.0f) ? (1.0f - r) : r;
    return x * phi;
}

__device__ __forceinline__ short f2bf(float f) {
    union { float f; unsigned u; } v; v.f = f;
    return (short)((v.u + 0x7FFFu + ((v.u >> 16) & 1u)) >> 16);
}

// ---- kA: blocks 0..511: LN -> W_in GEMM -> gelu -> gpart/ppart partial stores
//          -> h_local @ W1[0:128] -> At (MFMA-tiled). 4 rows/block.
//      blocks 512..543: W2 -> bf16 B-fragment tiling [n/16][k/8][n%16][k%8]. ----
// At layout: At[b][row/16][c/8][row%16][c%8].
__global__ __launch_bounds__(256) void kA_fused(
        const float* __restrict__ x, const float* __restrict__ ln_g,
        const float* __restrict__ ln_b, const float* __restrict__ W_in,
        const float* __restrict__ b_in, const float* __restrict__ policy,
        const float* __restrict__ W1, const float* __restrict__ W2,
        float* __restrict__ At, float* __restrict__ gpart,
        float* __restrict__ ppart, short* __restrict__ W2T) {
    int t = threadIdx.x;
    int blk = blockIdx.x;
    if (blk >= 512) {
        int u = (blk - 512) * 256 + t;
        int n = u >> 6, kg = u & 63;          // n 0..127, kg 0..63 (4 k's each)
        short4 v;
        v.x = f2bf(W2[(kg * 4 + 0) * HALF + n]);
        v.y = f2bf(W2[(kg * 4 + 1) * HALF + n]);
        v.z = f2bf(W2[(kg * 4 + 2) * HALF + n]);
        v.w = f2bf(W2[(kg * 4 + 3) * HALF + n]);
        // tiled addr for (n, k=kg*4..+3): ((n>>4)*32 + (kg>>1))*128 + (n&15)*8 + (kg&1)*4
        *(short4*)(W2T + ((size_t)((n >> 4) * 32 + (kg >> 1)) * 128
                          + (n & 15) * 8 + (kg & 1) * 4)) = v;
        return;
    }
    __shared__ float xst[CC][4];
    __shared__ float hst[HALF][4];
    int wave = t >> 6, lane = t & 63;
    int row0 = blk * 4;
    const float* xr = x + (size_t)(row0 + wave) * CC;
    float v0 = xr[lane], v1 = xr[lane + 64], v2 = xr[lane + 128], v3 = xr[lane + 192];
    float s = v0 + v1 + v2 + v3;
    for (int off = 32; off; off >>= 1) s += __shfl_down(s, off);
    s = __shfl(s, 0);
    float mu = s * (1.0f / CC);
    float d0 = v0 - mu, d1 = v1 - mu, d2 = v2 - mu, d3 = v3 - mu;
    float vs = d0 * d0 + d1 * d1 + d2 * d2 + d3 * d3;
    for (int off = 32; off; off >>= 1) vs += __shfl_down(vs, off);
    vs = __shfl(vs, 0);
    float rstd = rsqrtf(vs * (1.0f / CC) + 1e-5f);
    xst[lane][wave]       = d0 * rstd * ln_g[lane]       + ln_b[lane];
    xst[lane + 64][wave]  = d1 * rstd * ln_g[lane + 64]  + ln_b[lane + 64];
    xst[lane + 128][wave] = d2 * rstd * ln_g[lane + 128] + ln_b[lane + 128];
    xst[lane + 192][wave] = d3 * rstd * ln_g[lane + 192] + ln_b[lane + 192];
    __syncthreads();
    // GEMM1: h[row0+r][t] = gelu(LN(x)@W_in + b_in)
    float a0 = b_in[t], a1 = a0, a2 = a0, a3 = a0;
    #pragma unroll 8
    for (int k = 0; k < CC; ++k) {
        float4 xv = *(const float4*)xst[k];     // uniform addr -> broadcast
        float wv = W_in[k * CC + t];
        a0 = fmaf(xv.x, wv, a0); a1 = fmaf(xv.y, wv, a1);
        a2 = fmaf(xv.z, wv, a2); a3 = fmaf(xv.w, wv, a3);
    }
    float h0 = gelu_fast(a0), h1 = gelu_fast(a1), h2 = gelu_fast(a2), h3 = gelu_fast(a3);
    float p0 = policy[row0], p1 = policy[row0 + 1], p2 = policy[row0 + 2], p3 = policy[row0 + 3];
    if (t < HALF) {
        hst[t][0] = h0; hst[t][1] = h1; hst[t][2] = h2; hst[t][3] = h3;
    } else {
        gpart[(size_t)blk * HALF + (t - HALF)] = h0 * p0 + h1 * p1 + h2 * p2 + h3 * p3;
    }
    if (t == 0) ppart[blk] = p0 + p1 + p2 + p3;
    __syncthreads();
    // GEMM2: A[row0+r][t] = h_local[row0+r] @ W1[0:128]
    float c0 = 0, c1 = 0, c2 = 0, c3 = 0;
    #pragma unroll 8
    for (int k = 0; k < HALF; ++k) {
        float4 hv = *(const float4*)hst[k];     // uniform addr -> broadcast
        float wv = W1[k * CC + t];
        c0 = fmaf(hv.x, wv, c0); c1 = fmaf(hv.y, wv, c1);
        c2 = fmaf(hv.z, wv, c2); c3 = fmaf(hv.w, wv, c3);
    }
    int b = row0 >> 10;
    int lr = row0 & (NN - 1);
    size_t tb = ((size_t)(b * 64 + (lr >> 4)) * 32 + (t >> 3)) * 128 + (t & 7);
    int r16 = lr & 15;
    At[tb + (r16 + 0) * 8] = c0;
    At[tb + (r16 + 1) * 8] = c1;
    At[tb + (r16 + 2) * 8] = c2;
    At[tb + (r16 + 3) * 8] = c3;
}

// ---- kB: Qc[b,i] = q@W1[256:512] + glob@W1[128:256] + b1; glob reduced
//          redundantly per block from gpart/ppart (no atomics, no memset). ----
__global__ __launch_bounds__(256) void kB_qc(
        const float* __restrict__ query, const float* __restrict__ W1,
        const float* __restrict__ gpart, const float* __restrict__ ppart,
        const float* __restrict__ b1, float* __restrict__ Qc) {
    __shared__ float gls[HALF];
    __shared__ float qs[CC];
    __shared__ float psS;
    int blk = blockIdx.x, t = threadIdx.x;
    int b = blk / NQ, i = blk % NQ;
    if (t < 64) {
        const float* pp = ppart + b * 256;
        float ps = pp[t] + pp[t + 64] + pp[t + 128] + pp[t + 192];
        for (int off = 32; off; off >>= 1) ps += __shfl_down(ps, off);
        if (t == 0) psS = ps;
    }
    if (t < HALF) {
        const float* gp = gpart + (size_t)b * 256 * HALF + t;
        float s = 0.f;
        #pragma unroll 8
        for (int ch = 0; ch < 256; ++ch) s += gp[ch * HALF];
        gls[t] = s;
    }
    qs[t] = query[(size_t)(i * BB + b) * CC + t];
    __syncthreads();
    float inv_ps = 1.0f / psS;
    float g = b1[t];
    #pragma unroll 8
    for (int k = 0; k < HALF; ++k)
        g = fmaf(gls[k] * inv_ps, W1[(HALF + k) * CC + t], g);
    #pragma unroll 8
    for (int k = 0; k < CC; ++k)
        g = fmaf(qs[k], W1[(2 * HALF + k) * CC + t], g);
    Qc[(size_t)blk * CC + t] = g;
}

// ---- k5: barrier-free, LDS-free. In-register z1 frags from tiled At; B-frags
//          loaded directly from L2-resident MFMA-tiled W2T; gelu -> W3 -> lsm. ----
// Block M=64, N=128; 4 waves, wave-tile 16x128; acc 32 AGPR.
__global__ __launch_bounds__(256, 6) void k5_main(
        const float* __restrict__ At, const float* __restrict__ Qc,
        const short* __restrict__ W2T, const float* __restrict__ b2,
        const float* __restrict__ W3, const float* __restrict__ b3,
        float* __restrict__ out) {
    int t = threadIdx.x;
    int lane = t & 63, w = t >> 6;
    int col16 = lane & 15, quad = lane >> 4;
    int blk = blockIdx.x;
    int jt = blk & 15;
    int iq = (blk >> 4) % NQ;
    int b  = blk / (16 * NQ);
    const float* Abase = At + ((size_t)(b * 64 + jt * 4 + w) * 32) * 128 + col16 * 8;
    const float* Qrow = Qc + (size_t)(b * NQ + iq) * CC;
    // B-frag base for this lane: tile (ni, kq=kt*4+quad), row col16
    const short* Bbase = W2T + (size_t)quad * 128 + col16 * 8;

    f32x4 acc[8];
    #pragma unroll
    for (int ni = 0; ni < 8; ++ni) acc[ni] = (f32x4){0.f, 0.f, 0.f, 0.f};

    #pragma unroll
    for (int kt = 0; kt < 8; ++kt) {
        int k0 = kt * 32 + quad * 8;
        float4 q0 = *(const float4*)(Qrow + k0);
        float4 q1 = *(const float4*)(Qrow + k0 + 4);
        const float* Ap = Abase + (size_t)(kt * 4 + quad) * 128;
        float4 a0 = *(const float4*)(Ap);
        float4 a1 = *(const float4*)(Ap + 4);
        union { bf16x8 v; short s[8]; } u;
        u.s[0] = f2bf(gelu_fast(a0.x + q0.x));
        u.s[1] = f2bf(gelu_fast(a0.y + q0.y));
        u.s[2] = f2bf(gelu_fast(a0.z + q0.z));
        u.s[3] = f2bf(gelu_fast(a0.w + q0.w));
        u.s[4] = f2bf(gelu_fast(a1.x + q1.x));
        u.s[5] = f2bf(gelu_fast(a1.y + q1.y));
        u.s[6] = f2bf(gelu_fast(a1.z + q1.z));
        u.s[7] = f2bf(gelu_fast(a1.w + q1.w));
        const short* Bk = Bbase + (size_t)(kt * 4) * 128;
        #pragma unroll
        for (int ni = 0; ni < 8; ++ni) {
            bf16x8 bfv = *(const bf16x8*)(Bk + (size_t)ni * 32 * 128);
            acc[ni] = __builtin_amdgcn_mfma_f32_16x16x32_bf16(u.v, bfv, acc[ni], 0, 0, 0);
        }
    }

    // epilogue: z2 = gelu(acc + b2); logits = z2@W3; reduce over col16; lsm
    float p0[4] = {0, 0, 0, 0}, p1[4] = {0, 0, 0, 0};
    #pragma unroll
    for (int ni = 0; ni < 8; ++ni) {
        int c = ni * 16 + col16;
        float bb = b2[c];
        float2 w3v = *(const float2*)(W3 + c * 2);
        #pragma unroll
        for (int r = 0; r < 4; ++r) {
            float z = gelu_fast(acc[ni][r] + bb);
            p0[r] = fmaf(z, w3v.x, p0[r]);
            p1[r] = fmaf(z, w3v.y, p1[r]);
        }
    }
    float b30 = b3[0], b31 = b3[1];
    #pragma unroll
    for (int r = 0; r < 4; ++r) {
        float s0 = p0[r], s1 = p1[r];
        #pragma unroll
        for (int off = 1; off < 16; off <<= 1) {
            s0 += __shfl_xor(s0, off);
            s1 += __shfl_xor(s1, off);
        }
        if (col16 == 0) {
            float z0 = s0 + b30, z1v = s1 + b31;
            float m = fmaxf(z0, z1v);
            float lse = m + __logf(__expf(z0 - m) + __expf(z1v - m));
            int j = jt * 64 + w * 16 + quad * 4 + r;
            *(float2*)(out + ((size_t)(b * NQ + iq) * NN + j) * 2) =
                make_float2(z0 - lse, z1v - lse);
        }
    }
}

extern "C" void kernel_launch(void* const* d_in, const int* in_sizes, int n_in,
                              void* d_out, int out_size, void* d_ws, size_t ws_size,
                              hipStream_t stream) {
    const float* x      = (const float*)d_in[0];
    const float* query  = (const float*)d_in[1];
    const float* policy = (const float*)d_in[2];
    const float* ln_g   = (const float*)d_in[3];
    const float* ln_b   = (const float*)d_in[4];
    const float* W_in   = (const float*)d_in[5];
    const float* b_in   = (const float*)d_in[6];
    const float* W1     = (const float*)d_in[7];
    const float* b1     = (const float*)d_in[8];
    const float* W2     = (const float*)d_in[9];
    const float* b2     = (const float*)d_in[10];
    const float* W3     = (const float*)d_in[11];
    const float* b3     = (const float*)d_in[12];
    float* out = (float*)d_out;

    float* ws    = (float*)d_ws;
    float* At    = ws;                 // 2*1024*256 fp32 (MFMA-tiled)
    float* Qc    = ws + 524288;        // 200*256
    float* gpart = ws + 575488;        // 512*128
    float* ppart = ws + 641024;        // 512
    short* W2T   = (short*)(ws + 641536);  // 128*256 bf16, MFMA-B-tiled (64 KB)

    kA_fused<<<544, 256, 0, stream>>>(x, ln_g, ln_b, W_in, b_in, policy,
                                      W1, W2, At, gpart, ppart, W2T);
    kB_qc<<<BB * NQ, 256, 0, stream>>>(query, W1, gpart, ppart, b1, Qc);
    k5_main<<<BB * NQ * (NN / 64), 256, 0, stream>>>(At, Qc, W2T, b2, W3, b3, out);
}

// Round 7
// 155.431 us; speedup vs baseline: 1.1918x; 1.1918x over previous
//
#include <hip/hip_runtime.h>
#include <math.h>

#define BB 2
#define NN 1024
#define CC 256
#define NQ 100
#define HALF 128

typedef __attribute__((ext_vector_type(8))) short bf16x8;
typedef __attribute__((ext_vector_type(4))) float f32x4;

__device__ __forceinline__ float exp2_fast(float v) {
#if __has_builtin(__builtin_amdgcn_exp2f)
    return __builtin_amdgcn_exp2f(v);
#else
    return __expf(0.69314718056f * v);
#endif
}

// gelu tanh-form: x * sigmoid(2*c1*(x + c2*x^3)); |err vs erf-gelu| <= ~3e-4.
// Constants pre-folded with log2(e): A = 2*0.7978845608*1.44269504, B = A*0.044715.
__device__ __forceinline__ float gelu_fast(float x) {
    float x2 = x * x;
    float v = x * fmaf(0.10293942f, x2, 2.30211418f);
    float e = exp2_fast(v);                    // e^{2c1(x+c2 x^3)}
    float r = __builtin_amdgcn_rcpf(1.0f + e);
    return fmaf(-x, r, x);                     // x * (1 - 1/(1+e))
}

// fp32 -> bf16 RNE
__device__ __forceinline__ short f2bf(float f) {
    union { float f; unsigned u; } v; v.f = f;
    return (short)((v.u + 0x7FFFu + ((v.u >> 16) & 1u)) >> 16);
}

// ---- kA: LN -> W_in GEMM -> gelu -> gpart/ppart partial stores
//          -> h_local @ W1[0:128] -> At (MFMA-A-frag tiled). 4 rows/block. ----
// At layout: At[((b*64 + row/16)*32 + k/8)*128 + (row%16)*8 + k%8].
__global__ __launch_bounds__(256) void kA_fused(
        const float* __restrict__ x, const float* __restrict__ ln_g,
        const float* __restrict__ ln_b, const float* __restrict__ W_in,
        const float* __restrict__ b_in, const float* __restrict__ policy,
        const float* __restrict__ W1, float* __restrict__ At,
        float* __restrict__ gpart, float* __restrict__ ppart) {
    __shared__ float xst[CC][4];
    __shared__ float hst[HALF][4];
    int t = threadIdx.x;
    int wave = t >> 6, lane = t & 63;
    int blk = blockIdx.x;
    int row0 = blk * 4;
    const float* xr = x + (size_t)(row0 + wave) * CC;
    float v0 = xr[lane], v1 = xr[lane + 64], v2 = xr[lane + 128], v3 = xr[lane + 192];
    float s = v0 + v1 + v2 + v3;
    for (int off = 32; off; off >>= 1) s += __shfl_down(s, off);
    s = __shfl(s, 0);
    float mu = s * (1.0f / CC);
    float d0 = v0 - mu, d1 = v1 - mu, d2 = v2 - mu, d3 = v3 - mu;
    float vs = d0 * d0 + d1 * d1 + d2 * d2 + d3 * d3;
    for (int off = 32; off; off >>= 1) vs += __shfl_down(vs, off);
    vs = __shfl(vs, 0);
    float rstd = rsqrtf(vs * (1.0f / CC) + 1e-5f);
    xst[lane][wave]       = d0 * rstd * ln_g[lane]       + ln_b[lane];
    xst[lane + 64][wave]  = d1 * rstd * ln_g[lane + 64]  + ln_b[lane + 64];
    xst[lane + 128][wave] = d2 * rstd * ln_g[lane + 128] + ln_b[lane + 128];
    xst[lane + 192][wave] = d3 * rstd * ln_g[lane + 192] + ln_b[lane + 192];
    __syncthreads();
    // GEMM1: h[row0+r][t] = gelu(LN(x)@W_in + b_in)
    float a0 = b_in[t], a1 = a0, a2 = a0, a3 = a0;
    #pragma unroll 8
    for (int k = 0; k < CC; ++k) {
        float4 xv = *(const float4*)xst[k];     // uniform addr -> broadcast
        float wv = W_in[k * CC + t];
        a0 = fmaf(xv.x, wv, a0); a1 = fmaf(xv.y, wv, a1);
        a2 = fmaf(xv.z, wv, a2); a3 = fmaf(xv.w, wv, a3);
    }
    float h0 = gelu_fast(a0), h1 = gelu_fast(a1), h2 = gelu_fast(a2), h3 = gelu_fast(a3);
    float p0 = policy[row0], p1 = policy[row0 + 1], p2 = policy[row0 + 2], p3 = policy[row0 + 3];
    if (t < HALF) {
        hst[t][0] = h0; hst[t][1] = h1; hst[t][2] = h2; hst[t][3] = h3;
    } else {
        gpart[(size_t)blk * HALF + (t - HALF)] = h0 * p0 + h1 * p1 + h2 * p2 + h3 * p3;
    }
    if (t == 0) ppart[blk] = p0 + p1 + p2 + p3;
    __syncthreads();
    // GEMM2: A[row0+r][t] = h_local[row0+r] @ W1[0:128]
    float c0 = 0, c1 = 0, c2 = 0, c3 = 0;
    #pragma unroll 8
    for (int k = 0; k < HALF; ++k) {
        float4 hv = *(const float4*)hst[k];     // uniform addr -> broadcast
        float wv = W1[k * CC + t];
        c0 = fmaf(hv.x, wv, c0); c1 = fmaf(hv.y, wv, c1);
        c2 = fmaf(hv.z, wv, c2); c3 = fmaf(hv.w, wv, c3);
    }
    int b = row0 >> 10;
    int lr = row0 & (NN - 1);
    size_t tb = ((size_t)(b * 64 + (lr >> 4)) * 32 + (t >> 3)) * 128 + (t & 7);
    int r16 = lr & 15;
    At[tb + (r16 + 0) * 8] = c0;
    At[tb + (r16 + 1) * 8] = c1;
    At[tb + (r16 + 2) * 8] = c2;
    At[tb + (r16 + 3) * 8] = c3;
}

// ---- kB: blocks 0..199: Qc[b,i] = q@W1[256:512] + glob@W1[128:256] + b1
//          (glob reduced per block, 2-way parallel chunks);
//      blocks 200..231: W2 -> bf16 MFMA-B-frag tiling (coalesced reads). ----
// W2T layout: W2T[((n/16)*32 + k/8)*128 + (n%16)*8 + k%8].
__global__ __launch_bounds__(256) void kB_qc_prep(
        const float* __restrict__ query, const float* __restrict__ W1,
        const float* __restrict__ W2, const float* __restrict__ gpart,
        const float* __restrict__ ppart, const float* __restrict__ b1,
        float* __restrict__ Qc, short* __restrict__ W2T) {
    int blk = blockIdx.x, t = threadIdx.x;
    if (blk >= BB * NQ) {
        int u = (blk - BB * NQ) * 256 + t;    // 0..8191
        int n = u & 127;                       // lane-varying -> coalesced reads
        int kq = u >> 7;                       // 0..63, k = kq*4 + r
        short4 v;
        v.x = f2bf(W2[(kq * 4 + 0) * HALF + n]);
        v.y = f2bf(W2[(kq * 4 + 1) * HALF + n]);
        v.z = f2bf(W2[(kq * 4 + 2) * HALF + n]);
        v.w = f2bf(W2[(kq * 4 + 3) * HALF + n]);
        *(short4*)(W2T + (size_t)((n >> 4) * 32 + (kq >> 1)) * 128
                   + (n & 15) * 8 + (kq & 1) * 4) = v;
        return;
    }
    __shared__ float gl2[2][HALF];
    __shared__ float gls[HALF];
    __shared__ float qs[CC];
    __shared__ float pss;
    int b = blk / NQ, i = blk % NQ;
    int c = t & 127, hh = t >> 7;
    // glob numerator: 2 threads per c, 128 chunks each
    {
        const float* gp = gpart + ((size_t)b * 256 + hh * 128) * HALF + c;
        float s = 0.f;
        #pragma unroll 16
        for (int ch = 0; ch < 128; ++ch) s += gp[(size_t)ch * HALF];
        gl2[hh][c] = s;
    }
    if (t < 64) {
        const float* pp = ppart + b * 256;
        float ps = pp[t] + pp[t + 64] + pp[t + 128] + pp[t + 192];
        for (int off = 32; off; off >>= 1) ps += __shfl_down(ps, off);
        if (t == 0) pss = ps;
    }
    qs[t] = query[(size_t)(i * BB + b) * CC + t];
    __syncthreads();
    if (t < HALF) gls[t] = (gl2[0][t] + gl2[1][t]) / pss;
    __syncthreads();
    float g = b1[t];
    #pragma unroll 8
    for (int k = 0; k < HALF; ++k)
        g = fmaf(gls[k], W1[(HALF + k) * CC + t], g);
    #pragma unroll 8
    for (int k = 0; k < CC; ++k)
        g = fmaf(qs[k], W1[(2 * HALF + k) * CC + t], g);
    Qc[(size_t)blk * CC + t] = g;
}

// ---- k5: in-register z1 frags from tiled At; W2 staged per-32k-chunk in
//          frag-tiled LDS (dense, conflict-free); dbuf, 1 barrier/chunk. ----
// Block M=64, N=128; 4 waves, wave-tile 16x128; acc 32 AGPR.
// LDS chunk: 512 frag-rows x 8 shorts = 8 KB; read = lane-contiguous b128.
__global__ __launch_bounds__(256, 4) void k5_main(
        const float* __restrict__ At, const float* __restrict__ Qc,
        const short* __restrict__ W2T, const float* __restrict__ b2,
        const float* __restrict__ W3, const float* __restrict__ b3,
        float* __restrict__ out) {
    __shared__ short w2s[2][4096];   // 2 x 8 KB

    int t = threadIdx.x;
    int lane = t & 63, w = t >> 6;
    int col16 = lane & 15, quad = lane >> 4;
    int blk = blockIdx.x;
    int jt = blk & 15;
    int iq = (blk >> 4) % NQ;
    int b  = blk / (16 * NQ);
    const float* Abase = At + ((size_t)(b * 64 + jt * 4 + w) * 32) * 128 + col16 * 8;
    const float* Qrow = Qc + (size_t)(b * NQ + iq) * CC;
    // staging: thread t handles frag-units u=t (rows 0..63 of W2) and u=t+256
    // global src for chunk kt: Wg + kt*512 (and +16384 for the second half)
    const short* Wg = W2T + (size_t)((t >> 6) * 32 + ((t >> 4) & 3)) * 128 + (t & 15) * 8;

    f32x4 acc[8];
    #pragma unroll
    for (int ni = 0; ni < 8; ++ni) acc[ni] = (f32x4){0.f, 0.f, 0.f, 0.f};

    // prologue: chunk 0 -> buf0; preload chunk 1 -> regs; A/Q(0) -> regs
    bf16x8 nx0 = *(const bf16x8*)(Wg);
    bf16x8 nx1 = *(const bf16x8*)(Wg + 16384);
    float4 a0 = *(const float4*)(Abase + quad * 128);
    float4 a1 = *(const float4*)(Abase + quad * 128 + 4);
    float4 q0 = *(const float4*)(Qrow + quad * 8);
    float4 q1 = *(const float4*)(Qrow + quad * 8 + 4);
    *(bf16x8*)&w2s[0][t * 8] = nx0;
    *(bf16x8*)&w2s[0][2048 + t * 8] = nx1;
    nx0 = *(const bf16x8*)(Wg + 512);
    nx1 = *(const bf16x8*)(Wg + 16384 + 512);
    __syncthreads();

    #pragma unroll
    for (int kt = 0; kt < 8; ++kt) {
        int buf = kt & 1;
        // write chunk kt+1 into the other buffer (safe: its readers finished
        // before the barrier that ended iter kt-1)
        if (kt < 7) {
            *(bf16x8*)&w2s[1 - buf][t * 8] = nx0;
            *(bf16x8*)&w2s[1 - buf][2048 + t * 8] = nx1;
        }
        if (kt < 6) {
            nx0 = *(const bf16x8*)(Wg + (kt + 2) * 512);
            nx1 = *(const bf16x8*)(Wg + 16384 + (kt + 2) * 512);
        }
        // z1 frag = gelu(A + Q) for this chunk (A/Q loaded last iter)
        union { bf16x8 v; short s[8]; } fr;
        fr.s[0] = f2bf(gelu_fast(a0.x + q0.x));
        fr.s[1] = f2bf(gelu_fast(a0.y + q0.y));
        fr.s[2] = f2bf(gelu_fast(a0.z + q0.z));
        fr.s[3] = f2bf(gelu_fast(a0.w + q0.w));
        fr.s[4] = f2bf(gelu_fast(a1.x + q1.x));
        fr.s[5] = f2bf(gelu_fast(a1.y + q1.y));
        fr.s[6] = f2bf(gelu_fast(a1.z + q1.z));
        fr.s[7] = f2bf(gelu_fast(a1.w + q1.w));
        // prefetch A/Q for kt+1 (in flight during LDS+MFMA)
        if (kt < 7) {
            const float* Ap = Abase + (size_t)((kt + 1) * 4 + quad) * 128;
            a0 = *(const float4*)(Ap);
            a1 = *(const float4*)(Ap + 4);
            q0 = *(const float4*)(Qrow + (kt + 1) * 32 + quad * 8);
            q1 = *(const float4*)(Qrow + (kt + 1) * 32 + quad * 8 + 4);
        }
        // B frags: lane-contiguous dense reads, zero conflicts
        #pragma unroll
        for (int ni = 0; ni < 8; ++ni) {
            bf16x8 bv = *(const bf16x8*)&w2s[buf][(ni * 64 + lane) * 8];
            acc[ni] = __builtin_amdgcn_mfma_f32_16x16x32_bf16(fr.v, bv, acc[ni], 0, 0, 0);
        }
        if (kt < 7) __syncthreads();
    }

    // epilogue: z2 = gelu(acc + b2); logits = z2@W3; reduce over col16; lsm
    float p0[4] = {0, 0, 0, 0}, p1[4] = {0, 0, 0, 0};
    #pragma unroll
    for (int ni = 0; ni < 8; ++ni) {
        int c = ni * 16 + col16;
        float bb = b2[c];
        float2 w3v = *(const float2*)(W3 + c * 2);
        #pragma unroll
        for (int r = 0; r < 4; ++r) {
            float z = gelu_fast(acc[ni][r] + bb);
            p0[r] = fmaf(z, w3v.x, p0[r]);
            p1[r] = fmaf(z, w3v.y, p1[r]);
        }
    }
    float b30 = b3[0], b31 = b3[1];
    #pragma unroll
    for (int r = 0; r < 4; ++r) {
        float s0 = p0[r], s1 = p1[r];
        #pragma unroll
        for (int off = 1; off < 16; off <<= 1) {
            s0 += __shfl_xor(s0, off);
            s1 += __shfl_xor(s1, off);
        }
        if (col16 == 0) {
            float z0 = s0 + b30, z1v = s1 + b31;
            float m = fmaxf(z0, z1v);
            float lse = m + __logf(__expf(z0 - m) + __expf(z1v - m));
            int j = jt * 64 + w * 16 + quad * 4 + r;
            *(float2*)(out + ((size_t)(b * NQ + iq) * NN + j) * 2) =
                make_float2(z0 - lse, z1v - lse);
        }
    }
}

extern "C" void kernel_launch(void* const* d_in, const int* in_sizes, int n_in,
                              void* d_out, int out_size, void* d_ws, size_t ws_size,
                              hipStream_t stream) {
    const float* x      = (const float*)d_in[0];
    const float* query  = (const float*)d_in[1];
    const float* policy = (const float*)d_in[2];
    const float* ln_g   = (const float*)d_in[3];
    const float* ln_b   = (const float*)d_in[4];
    const float* W_in   = (const float*)d_in[5];
    const float* b_in   = (const float*)d_in[6];
    const float* W1     = (const float*)d_in[7];
    const float* b1     = (const float*)d_in[8];
    const float* W2     = (const float*)d_in[9];
    const float* b2     = (const float*)d_in[10];
    const float* W3     = (const float*)d_in[11];
    const float* b3     = (const float*)d_in[12];
    float* out = (float*)d_out;

    float* ws    = (float*)d_ws;
    float* At    = ws;                 // 2*1024*256 fp32 (MFMA-A-frag tiled)
    float* Qc    = ws + 524288;        // 200*256
    float* gpart = ws + 575488;        // 512*128
    float* ppart = ws + 641024;        // 512
    short* W2T   = (short*)(ws + 641536);  // 128*256 bf16, MFMA-B-frag tiled

    kA_fused<<<512, 256, 0, stream>>>(x, ln_g, ln_b, W_in, b_in, policy,
                                      W1, At, gpart, ppart);
    kB_qc_prep<<<BB * NQ + 32, 256, 0, stream>>>(query, W1, W2, gpart, ppart,
                                                 b1, Qc, W2T);
    k5_main<<<BB * NQ * (NN / 64), 256, 0, stream>>>(At, Qc, W2T, b2, W3, b3, out);
}